// Round 7
// baseline (114.714 us; speedup 1.0000x reference)
//
#include <hip/hip_runtime.h>
#include <hip/hip_bf16.h>

#define MM 512
#define ROWSZ (66 * 8)    // shorts per LDS row (66 cols x 8 ch)

typedef short bf16x8 __attribute__((ext_vector_type(8)));
typedef float f32x4  __attribute__((ext_vector_type(4)));

static __device__ inline short f2bf(float f) {
    __hip_bfloat16 h = __float2bfloat16(f);
    return *reinterpret_cast<short*>(&h);
}

// One block per output row b in [0,2048): e = b>>9, sample = idx[b].
// GEMM per 16-pixel tile: D[16px,16co], 3 MFMA (one per kernel row kh):
//   MFMA m: A-frag = image row (rl-1+m), lane(g,p) reads col CB+p+g-1
//           B_m k-rows (g*8..g*8+7) = W3[kh=m][kw=g][ch][cout] for cols 8-15
//   conv1 (cols 0-7) lives in B_1, group g=1 (center tap) = W1.
// ROW-RING: the read for row rl+2 is used as A2 now, A1 next iter, A0 after
// -> ONE ds_read_b128 per lane per rl (was 3). sx (skip channel sums) is
// accumulated on the VALU from the fp32 staging regs (each pixel staged
// exactly once), replacing the identity-B MFMA.
// Strip buffer L0..L17 = image rows 16s-1..16s+16, linear (immediate offsets).
// Each image row fetched from HBM exactly once (overlap rows carried in regs).
__global__ __launch_bounds__(256, 4)
void conv_moe_mfma(const float* __restrict__ x,
                   const int*   __restrict__ idx,
                   const float* __restrict__ W1,
                   const float* __restrict__ W3,
                   const float* __restrict__ Wsk,
                   const float* __restrict__ Wd,
                   const float* __restrict__ cmask,
                   float*       __restrict__ out)
{
    __shared__ short xbf[18][66][8];   // 19 KB, col halo at 0 and 65
    __shared__ float red[4][16];
    __shared__ float redx[4][8];
    __shared__ float rsum[16];
    __shared__ float rsumx[8];
    __shared__ float pooledS[16];

    const int b    = blockIdx.x;
    const int e    = b >> 9;
    const int tid  = threadIdx.x;
    const int lane = tid & 63;
    const int wid  = tid >> 6;
    const int g    = lane >> 4;   // lane group 0..3 (kw column offset; 3 = idle)
    const int p    = lane & 15;   // A: pixel col within tile; B/D: cout column
    const int CB   = wid << 4;    // this wave's 16-col tile base

    const int samp = idx[b];
    const float* xb = x + (size_t)samp * 32768;

    // ---- B fragments ----
    const float* w3 = W3 + e * 576;  // [tap][cin][cout] (tap=kh*3+kw)
    const float* w1 = W1 + e * 64;   // [cin][cout]
    bf16x8 B0, B1, B2;
    #pragma unroll
    for (int j = 0; j < 8; ++j) {
        float v0 = 0.f, v1 = 0.f, v2 = 0.f;
        if (g < 3) {
            if (p >= 8) {               // conv3 couts: tap (m, g)
                v0 = w3[(0 * 3 + g) * 64 + j * 8 + (p - 8)];
                v1 = w3[(1 * 3 + g) * 64 + j * 8 + (p - 8)];
                v2 = w3[(2 * 3 + g) * 64 + j * 8 + (p - 8)];
            } else if (g == 1) {        // conv1 couts: center tap -> B1, g==1
                v1 = w1[j * 8 + p];
            }
        }
        B0[j] = f2bf(v0); B1[j] = f2bf(v1); B2[j] = f2bf(v2);
    }

    // ---- per-lane A read offset (shorts): col = CB + p + g - 1 (+1 halo) ----
    const int gi  = (g < 3) ? g : 2;       // g==3 duplicates g==2 (B rows zero)
    const int offA = (CB + p + gi) * 8;

    // ---- zero column halos once ----
    if (tid < 36) {
        const int rr = tid >> 1, side = tid & 1;
        bf16x8 zv = {0,0,0,0,0,0,0,0};
        *(bf16x8*)&xbf[rr][side ? 65 : 0][0] = zv;
    }

    const float4 z4 = make_float4(0.f, 0.f, 0.f, 0.f);
    float4 ra[5][2];
    float4 sxa = z4, sxb = z4;   // per-thread raw-x channel sums (VALU, fp32)

    // ---- initial stage: image rows -1..16 -> L0..L17 (1152 px) ----
    #pragma unroll
    for (int j5 = 0; j5 < 5; ++j5) {
        const int j = j5 * 256 + tid;
        ra[j5][0] = z4; ra[j5][1] = z4;
        if (j < 1152) {
            const int lrow = j >> 6, c = j & 63;
            const int r = lrow - 1;
            if (r >= 0) {
                const float4* s4 = (const float4*)(xb + (((r << 6) + c) << 3));
                ra[j5][0] = s4[0];
                ra[j5][1] = s4[1];
            }
        }
    }
    #pragma unroll
    for (int j5 = 0; j5 < 5; ++j5) {
        const int j = j5 * 256 + tid;
        if (j < 1152) {
            const int lrow = j >> 6, c = j & 63;
            sxa.x += ra[j5][0].x; sxa.y += ra[j5][0].y;
            sxa.z += ra[j5][0].z; sxa.w += ra[j5][0].w;
            sxb.x += ra[j5][1].x; sxb.y += ra[j5][1].y;
            sxb.z += ra[j5][1].z; sxb.w += ra[j5][1].w;
            bf16x8 v;
            v[0] = f2bf(ra[j5][0].x); v[1] = f2bf(ra[j5][0].y);
            v[2] = f2bf(ra[j5][0].z); v[3] = f2bf(ra[j5][0].w);
            v[4] = f2bf(ra[j5][1].x); v[5] = f2bf(ra[j5][1].y);
            v[6] = f2bf(ra[j5][1].z); v[7] = f2bf(ra[j5][1].w);
            *(bf16x8*)&xbf[lrow][c + 1][0] = v;
        }
    }
    __syncthreads();

    f32x4 ssum = {0.f, 0.f, 0.f, 0.f};  // per-lane relu'd conv sums

    #pragma unroll 1
    for (int s = 0; s < 4; ++s) {
        // async: issue global loads for strip s+1's 16 NEW rows
        if (s < 3) {
            const int rbase = 16 * (s + 1) + 1;
            #pragma unroll
            for (int j5 = 0; j5 < 4; ++j5) {
                const int j = j5 * 256 + tid;
                const int lrow = j >> 6, c = j & 63;
                const int r = rbase + lrow;
                ra[j5][0] = z4; ra[j5][1] = z4;
                if (r < 64) {
                    const float4* s4 = (const float4*)(xb + (((r << 6) + c) << 3));
                    ra[j5][0] = s4[0];
                    ra[j5][1] = s4[1];
                }
            }
        }

        // ---- compute strip s: row-ring, 1 ds_read per rl ----
        {
            const short* base = &xbf[0][0][0] + offA;
            bf16x8 A0 = *(const bf16x8*)(base + 0 * ROWSZ);
            bf16x8 A1 = *(const bf16x8*)(base + 1 * ROWSZ);
            bf16x8 A2 = *(const bf16x8*)(base + 2 * ROWSZ);
            #pragma unroll
            for (int rl = 0; rl < 16; ++rl) {
                bf16x8 A3 = A2;
                if (rl < 15) A3 = *(const bf16x8*)(base + (rl + 3) * ROWSZ);
                f32x4 d = {0.f, 0.f, 0.f, 0.f};
                d = __builtin_amdgcn_mfma_f32_16x16x32_bf16(A0, B0, d, 0, 0, 0);
                d = __builtin_amdgcn_mfma_f32_16x16x32_bf16(A1, B1, d, 0, 0, 0);
                d = __builtin_amdgcn_mfma_f32_16x16x32_bf16(A2, B2, d, 0, 0, 0);
                ssum[0] += fmaxf(d[0], 0.f);
                ssum[1] += fmaxf(d[1], 0.f);
                ssum[2] += fmaxf(d[2], 0.f);
                ssum[3] += fmaxf(d[3], 0.f);
                A0 = A1; A1 = A2; A2 = A3;
            }
        }

        // carry the 2 overlap rows (L16,L17 = next strip's L0,L1) in regs
        bf16x8 rcopy;
        if (s < 3 && tid < 128)
            rcopy = *(const bf16x8*)&xbf[16 + (tid >> 6)][(tid & 63) + 1][0];

        __syncthreads();   // all reads of this strip done before overwrite

        if (s < 3) {
            if (tid < 128)
                *(bf16x8*)&xbf[tid >> 6][(tid & 63) + 1][0] = rcopy;
            #pragma unroll
            for (int j5 = 0; j5 < 4; ++j5) {
                const int j = j5 * 256 + tid;
                const int lrow = 2 + (j >> 6), c = j & 63;
                sxa.x += ra[j5][0].x; sxa.y += ra[j5][0].y;
                sxa.z += ra[j5][0].z; sxa.w += ra[j5][0].w;
                sxb.x += ra[j5][1].x; sxb.y += ra[j5][1].y;
                sxb.z += ra[j5][1].z; sxb.w += ra[j5][1].w;
                bf16x8 v;
                v[0] = f2bf(ra[j5][0].x); v[1] = f2bf(ra[j5][0].y);
                v[2] = f2bf(ra[j5][0].z); v[3] = f2bf(ra[j5][0].w);
                v[4] = f2bf(ra[j5][1].x); v[5] = f2bf(ra[j5][1].y);
                v[6] = f2bf(ra[j5][1].z); v[7] = f2bf(ra[j5][1].w);
                *(bf16x8*)&xbf[lrow][c + 1][0] = v;
            }
            __syncthreads();   // new strip visible before its reads
        }
    }

    // ---- reduce conv sums: lane holds col p partials ----
    float scon = ssum[0] + ssum[1] + ssum[2] + ssum[3];
    scon += __shfl_xor(scon, 16);
    scon += __shfl_xor(scon, 32);
    if (lane < 16) red[wid][lane] = scon;

    // ---- reduce raw-x sums: full 64-lane butterfly over 8 channels ----
    float sxv[8] = {sxa.x, sxa.y, sxa.z, sxa.w, sxb.x, sxb.y, sxb.z, sxb.w};
    #pragma unroll
    for (int i = 0; i < 8; ++i)
        #pragma unroll
        for (int off = 32; off > 0; off >>= 1)
            sxv[i] += __shfl_xor(sxv[i], off);
    if (lane == 0)
        #pragma unroll
        for (int i = 0; i < 8; ++i) redx[wid][i] = sxv[i];
    __syncthreads();

    if (tid < 16) rsum[tid]  = (red[0][tid] + red[1][tid] + red[2][tid] + red[3][tid]) * (1.f / 4096.f);
    if (tid < 8)  rsumx[tid] = (redx[0][tid] + redx[1][tid] + redx[2][tid] + redx[3][tid]) * (1.f / 4096.f);
    __syncthreads();

    if (tid < 16) {
        float acc = rsum[tid];   // cols 0-7: conv1 branch, 8-15: conv3 branch
        #pragma unroll
        for (int ci = 0; ci < 8; ++ci)
            acc += rsumx[ci] * Wsk[e * 128 + ci * 16 + tid];
        pooledS[tid] = acc;
    }
    __syncthreads();

    const float* wd = Wd + (size_t)e * 16 * MM;
    const float* cm = cmask + e * MM;
    #pragma unroll 1
    for (int m = tid; m < MM; m += 256) {
        float acc = 0.f;
        #pragma unroll
        for (int k = 0; k < 16; ++k) acc += pooledS[k] * wd[k * MM + m];
        out[(size_t)b * MM + m] = acc * cm[m];
    }
}

extern "C" void kernel_launch(void* const* d_in, const int* in_sizes, int n_in,
                              void* d_out, int out_size, void* d_ws, size_t ws_size,
                              hipStream_t stream) {
    const float* x    = (const float*)d_in[0];
    const int*   idx  = (const int*)  d_in[1];
    const float* W1   = (const float*)d_in[2];
    const float* W3   = (const float*)d_in[3];
    const float* Wsk  = (const float*)d_in[4];
    const float* Wd   = (const float*)d_in[5];
    const float* cmsk = (const float*)d_in[6];
    float* out = (float*)d_out;

    conv_moe_mfma<<<2048, 256, 0, stream>>>(x, idx, W1, W3, Wsk, Wd, cmsk, out);
}

// Round 8
// 49.448 us; speedup vs baseline: 2.3199x; 2.3199x over previous
//
#include <hip/hip_runtime.h>
#include <hip/hip_bf16.h>

#define MM 512
#define ROWSZ (66 * 8)    // shorts per LDS row (66 cols x 8 ch)

typedef short bf16x8 __attribute__((ext_vector_type(8)));
typedef float f32x4  __attribute__((ext_vector_type(4)));

static __device__ inline short f2bf(float f) {
    __hip_bfloat16 h = __float2bfloat16(f);
    return *reinterpret_cast<short*>(&h);
}

// One block per output row b in [0,2048): e = b>>9, sample = idx[b].
// GEMM per 16-pixel tile: D[16px,16co], 3 MFMA (one per kernel row kh):
//   MFMA m: A-frag = image row (rl-1+m), lane(g,p) reads col CB+p+g-1
//           B_m k-rows (g*8..g*8+7) = W3[kh=m][kw=g][ch][cout] for cols 8-15
//   conv1 (cols 0-7) lives in B_1, group g=1 (center tap) = W1.
// ROW-RING: the read for row rl+3 serves as A2 next iter, A1, then A0
// -> ONE ds_read_b128 per lane per output row (was 3).
// R8 fix vs R7: #pragma unroll 3 + peeled last iteration. Full unroll let
// the scheduler hoist all 16 ring loads -> ~64 extra live VGPRs -> scratch
// spill (the 2.2x regression). unroll 3 caps the live A-frags at ~5.
// sx (skip channel sums) accumulated on the VALU from fp32 staging regs.
// Strip buffer L0..L17 = image rows 16s-1..16s+16, linear (imm offsets).
// Each image row fetched from HBM exactly once (overlap rows carried in regs).
__global__ __launch_bounds__(256, 4)
void conv_moe_mfma(const float* __restrict__ x,
                   const int*   __restrict__ idx,
                   const float* __restrict__ W1,
                   const float* __restrict__ W3,
                   const float* __restrict__ Wsk,
                   const float* __restrict__ Wd,
                   const float* __restrict__ cmask,
                   float*       __restrict__ out)
{
    __shared__ short xbf[18][66][8];   // 19 KB, col halo at 0 and 65
    __shared__ float red[4][16];
    __shared__ float redx[4][8];
    __shared__ float rsum[16];
    __shared__ float rsumx[8];
    __shared__ float pooledS[16];

    const int b    = blockIdx.x;
    const int e    = b >> 9;
    const int tid  = threadIdx.x;
    const int lane = tid & 63;
    const int wid  = tid >> 6;
    const int g    = lane >> 4;   // lane group 0..3 (kw column offset; 3 = dup)
    const int p    = lane & 15;   // A: pixel col within tile; B/D: cout column
    const int CB   = wid << 4;    // this wave's 16-col tile base

    const int samp = idx[b];
    const float* xb = x + (size_t)samp * 32768;

    // ---- B fragments ----
    const float* w3 = W3 + e * 576;  // [tap][cin][cout] (tap=kh*3+kw)
    const float* w1 = W1 + e * 64;   // [cin][cout]
    bf16x8 B0, B1, B2;
    #pragma unroll
    for (int j = 0; j < 8; ++j) {
        float v0 = 0.f, v1 = 0.f, v2 = 0.f;
        if (g < 3) {
            if (p >= 8) {               // conv3 couts: tap (m, g)
                v0 = w3[(0 * 3 + g) * 64 + j * 8 + (p - 8)];
                v1 = w3[(1 * 3 + g) * 64 + j * 8 + (p - 8)];
                v2 = w3[(2 * 3 + g) * 64 + j * 8 + (p - 8)];
            } else if (g == 1) {        // conv1 couts: center tap -> B1, g==1
                v1 = w1[j * 8 + p];
            }
        }
        B0[j] = f2bf(v0); B1[j] = f2bf(v1); B2[j] = f2bf(v2);
    }

    // ---- per-lane A read offset (shorts): col = CB + p + g - 1 (+1 halo) ----
    const int gi  = (g < 3) ? g : 2;       // g==3 duplicates g==2 (B rows zero)
    const int offA = (CB + p + gi) * 8;

    // ---- zero column halos once ----
    if (tid < 36) {
        const int rr = tid >> 1, side = tid & 1;
        bf16x8 zv = {0,0,0,0,0,0,0,0};
        *(bf16x8*)&xbf[rr][side ? 65 : 0][0] = zv;
    }

    const float4 z4 = make_float4(0.f, 0.f, 0.f, 0.f);
    float4 ra[5][2];
    float4 sxa = z4, sxb = z4;   // per-thread raw-x channel sums (VALU, fp32)

    // ---- initial stage: image rows -1..16 -> L0..L17 (1152 px) ----
    #pragma unroll
    for (int j5 = 0; j5 < 5; ++j5) {
        const int j = j5 * 256 + tid;
        ra[j5][0] = z4; ra[j5][1] = z4;
        if (j < 1152) {
            const int lrow = j >> 6, c = j & 63;
            const int r = lrow - 1;
            if (r >= 0) {
                const float4* s4 = (const float4*)(xb + (((r << 6) + c) << 3));
                ra[j5][0] = s4[0];
                ra[j5][1] = s4[1];
            }
        }
    }
    #pragma unroll
    for (int j5 = 0; j5 < 5; ++j5) {
        const int j = j5 * 256 + tid;
        if (j < 1152) {
            const int lrow = j >> 6, c = j & 63;
            sxa.x += ra[j5][0].x; sxa.y += ra[j5][0].y;
            sxa.z += ra[j5][0].z; sxa.w += ra[j5][0].w;
            sxb.x += ra[j5][1].x; sxb.y += ra[j5][1].y;
            sxb.z += ra[j5][1].z; sxb.w += ra[j5][1].w;
            bf16x8 v;
            v[0] = f2bf(ra[j5][0].x); v[1] = f2bf(ra[j5][0].y);
            v[2] = f2bf(ra[j5][0].z); v[3] = f2bf(ra[j5][0].w);
            v[4] = f2bf(ra[j5][1].x); v[5] = f2bf(ra[j5][1].y);
            v[6] = f2bf(ra[j5][1].z); v[7] = f2bf(ra[j5][1].w);
            *(bf16x8*)&xbf[lrow][c + 1][0] = v;
        }
    }
    __syncthreads();

    f32x4 ssum = {0.f, 0.f, 0.f, 0.f};  // per-lane relu'd conv sums

    #pragma unroll 1
    for (int s = 0; s < 4; ++s) {
        // async: issue global loads for strip s+1's 16 NEW rows
        if (s < 3) {
            const int rbase = 16 * (s + 1) + 1;
            #pragma unroll
            for (int j5 = 0; j5 < 4; ++j5) {
                const int j = j5 * 256 + tid;
                const int lrow = j >> 6, c = j & 63;
                const int r = rbase + lrow;
                ra[j5][0] = z4; ra[j5][1] = z4;
                if (r < 64) {
                    const float4* s4 = (const float4*)(xb + (((r << 6) + c) << 3));
                    ra[j5][0] = s4[0];
                    ra[j5][1] = s4[1];
                }
            }
        }

        // ---- compute strip s: row-ring, 1 ds_read per output row ----
        {
            const short* base = &xbf[0][0][0] + offA;
            bf16x8 A0 = *(const bf16x8*)(base + 0 * ROWSZ);
            bf16x8 A1 = *(const bf16x8*)(base + 1 * ROWSZ);
            bf16x8 A2 = *(const bf16x8*)(base + 2 * ROWSZ);
            #pragma unroll 3
            for (int rl = 0; rl < 15; ++rl) {
                const bf16x8 A3 = *(const bf16x8*)(base + (rl + 3) * ROWSZ);
                f32x4 d = {0.f, 0.f, 0.f, 0.f};
                d = __builtin_amdgcn_mfma_f32_16x16x32_bf16(A0, B0, d, 0, 0, 0);
                d = __builtin_amdgcn_mfma_f32_16x16x32_bf16(A1, B1, d, 0, 0, 0);
                d = __builtin_amdgcn_mfma_f32_16x16x32_bf16(A2, B2, d, 0, 0, 0);
                ssum[0] += fmaxf(d[0], 0.f);
                ssum[1] += fmaxf(d[1], 0.f);
                ssum[2] += fmaxf(d[2], 0.f);
                ssum[3] += fmaxf(d[3], 0.f);
                A0 = A1; A1 = A2; A2 = A3;
            }
            // peeled rl = 15: uses L15,L16,L17 already in the ring
            f32x4 d = {0.f, 0.f, 0.f, 0.f};
            d = __builtin_amdgcn_mfma_f32_16x16x32_bf16(A0, B0, d, 0, 0, 0);
            d = __builtin_amdgcn_mfma_f32_16x16x32_bf16(A1, B1, d, 0, 0, 0);
            d = __builtin_amdgcn_mfma_f32_16x16x32_bf16(A2, B2, d, 0, 0, 0);
            ssum[0] += fmaxf(d[0], 0.f);
            ssum[1] += fmaxf(d[1], 0.f);
            ssum[2] += fmaxf(d[2], 0.f);
            ssum[3] += fmaxf(d[3], 0.f);
        }

        // carry the 2 overlap rows (L16,L17 = next strip's L0,L1) in regs
        bf16x8 rcopy;
        if (s < 3 && tid < 128)
            rcopy = *(const bf16x8*)&xbf[16 + (tid >> 6)][(tid & 63) + 1][0];

        __syncthreads();   // all reads of this strip done before overwrite

        if (s < 3) {
            if (tid < 128)
                *(bf16x8*)&xbf[tid >> 6][(tid & 63) + 1][0] = rcopy;
            #pragma unroll
            for (int j5 = 0; j5 < 4; ++j5) {
                const int j = j5 * 256 + tid;
                const int lrow = 2 + (j >> 6), c = j & 63;
                sxa.x += ra[j5][0].x; sxa.y += ra[j5][0].y;
                sxa.z += ra[j5][0].z; sxa.w += ra[j5][0].w;
                sxb.x += ra[j5][1].x; sxb.y += ra[j5][1].y;
                sxb.z += ra[j5][1].z; sxb.w += ra[j5][1].w;
                bf16x8 v;
                v[0] = f2bf(ra[j5][0].x); v[1] = f2bf(ra[j5][0].y);
                v[2] = f2bf(ra[j5][0].z); v[3] = f2bf(ra[j5][0].w);
                v[4] = f2bf(ra[j5][1].x); v[5] = f2bf(ra[j5][1].y);
                v[6] = f2bf(ra[j5][1].z); v[7] = f2bf(ra[j5][1].w);
                *(bf16x8*)&xbf[lrow][c + 1][0] = v;
            }
            __syncthreads();   // new strip visible before its reads
        }
    }

    // ---- reduce conv sums: lane holds col p partials ----
    float scon = ssum[0] + ssum[1] + ssum[2] + ssum[3];
    scon += __shfl_xor(scon, 16);
    scon += __shfl_xor(scon, 32);
    if (lane < 16) red[wid][lane] = scon;

    // ---- reduce raw-x sums: full 64-lane butterfly over 8 channels ----
    float sxv[8] = {sxa.x, sxa.y, sxa.z, sxa.w, sxb.x, sxb.y, sxb.z, sxb.w};
    #pragma unroll
    for (int i = 0; i < 8; ++i)
        #pragma unroll
        for (int off = 32; off > 0; off >>= 1)
            sxv[i] += __shfl_xor(sxv[i], off);
    if (lane == 0)
        #pragma unroll
        for (int i = 0; i < 8; ++i) redx[wid][i] = sxv[i];
    __syncthreads();

    if (tid < 16) rsum[tid]  = (red[0][tid] + red[1][tid] + red[2][tid] + red[3][tid]) * (1.f / 4096.f);
    if (tid < 8)  rsumx[tid] = (redx[0][tid] + redx[1][tid] + redx[2][tid] + redx[3][tid]) * (1.f / 4096.f);
    __syncthreads();

    if (tid < 16) {
        float acc = rsum[tid];   // cols 0-7: conv1 branch, 8-15: conv3 branch
        #pragma unroll
        for (int ci = 0; ci < 8; ++ci)
            acc += rsumx[ci] * Wsk[e * 128 + ci * 16 + tid];
        pooledS[tid] = acc;
    }
    __syncthreads();

    const float* wd = Wd + (size_t)e * 16 * MM;
    const float* cm = cmask + e * MM;
    #pragma unroll 1
    for (int m = tid; m < MM; m += 256) {
        float acc = 0.f;
        #pragma unroll
        for (int k = 0; k < 16; ++k) acc += pooledS[k] * wd[k * MM + m];
        out[(size_t)b * MM + m] = acc * cm[m];
    }
}

extern "C" void kernel_launch(void* const* d_in, const int* in_sizes, int n_in,
                              void* d_out, int out_size, void* d_ws, size_t ws_size,
                              hipStream_t stream) {
    const float* x    = (const float*)d_in[0];
    const int*   idx  = (const int*)  d_in[1];
    const float* W1   = (const float*)d_in[2];
    const float* W3   = (const float*)d_in[3];
    const float* Wsk  = (const float*)d_in[4];
    const float* Wd   = (const float*)d_in[5];
    const float* cmsk = (const float*)d_in[6];
    float* out = (float*)d_out;

    conv_moe_mfma<<<2048, 256, 0, stream>>>(x, idx, W1, W3, Wsk, Wd, cmsk, out);
}